// Round 14
// baseline (33.616 us; speedup 1.0000x reference)
//
#include <hip/hip_runtime.h>

// DQSN forward (v11): R12's tight-loop/per-element-guard structure (the only
// shape sustaining ~85-90% VALU issue) + R10's packed-fp32 body (the lowest
// measured VALU work). Loop, guard, epilogue identical to R12.
//
// out[b,o] = sum_h W2[o,h] * A[b,h] + b2[o] * (1 - 2^-16)
// A depends only on n = first j in 1..16 with fp32-cumsum_j(I) >= 1
// (hard reset to exactly 0.0 -> exactly periodic spike train, period n).
// n = med3(ceil(rcp(I)), 0, 17); provably equals the fp32-cumsum crossing
// outside the |r - nearest-int| < GUARD band (rcp err ~2e-6, cumsum shift
// <= 1.6e-5); in-band elements (P ~ 1e-4) fall back to the exact 16-step
// simulation, keeping decisions bit-faithful to the reference dynamics.
// A(n) via per-lane register table + ds_bpermute.

typedef float v2f __attribute__((ext_vector_type(2)));

constexpr int TSTEPS = 16;
constexpr int NB = 8;                  // batch rows per block (grid = 2048)
constexpr int NP = NB / 2;
constexpr float GUARD = 4e-5f;
constexpr float GTHR  = 0.5f - GUARD;

__global__ __launch_bounds__(256) void dqsn_fwd(
    const float* __restrict__ x,
    const float* __restrict__ W1,
    const float* __restrict__ b1,
    const float* __restrict__ W2,
    const float* __restrict__ b2,
    float* __restrict__ out,
    int B, int H)
{
    const int tid  = threadIdx.x;
    const int lane = tid & 63;
    const int b0   = blockIdx.x * NB;

    // per-lane A(n) table: lane l (1..16) holds A for period n=l.
    // lanes 0 and 17+ hold 0.0 (n=0: I<=0; n=17: no spike within 16 steps).
    float tval = 0.0f;
    if (lane >= 1 && lane <= TSTEPS) {
        unsigned mm = 0;
        for (int k = lane; k <= TSTEPS; k += lane) mm |= 1u << (k - 1);
        tval = (float)mm * 0x1p-16f;   // exact: mm < 2^17
    }
    const int table_reg = __float_as_int(tval);

    // x rows packed as (row 2ip, row 2ip+1) pairs for v_pk_fma_f32
    v2f xp0[NP], xp1[NP], xp2[NP], xp3[NP];
#pragma unroll
    for (int ip = 0; ip < NP; ++ip) {
        int ra = b0 + 2 * ip, rb = b0 + 2 * ip + 1;
        ra = (ra < B) ? ra : B - 1;
        rb = (rb < B) ? rb : B - 1;
        xp0[ip] = (v2f){x[ra * 4 + 0], x[rb * 4 + 0]};
        xp1[ip] = (v2f){x[ra * 4 + 1], x[rb * 4 + 1]};
        xp2[ip] = (v2f){x[ra * 4 + 2], x[rb * 4 + 2]};
        xp3[ip] = (v2f){x[ra * 4 + 3], x[rb * 4 + 3]};
    }

    // acc[i] = (out0, out1) partials for local row i
    v2f acc[NB];
#pragma unroll
    for (int i = 0; i < NB; ++i) acc[i] = (v2f){0.0f, 0.0f};

    // tight runtime loop, minimal live-set (R12's verified shape)
    for (int h = tid; h < H; h += 256) {
        const float4 w1 = *reinterpret_cast<const float4*>(W1 + (size_t)h * 4);
        const float bb  = b1[h];
        const v2f w2ab  = (v2f){W2[h], W2[H + h]};

#pragma unroll
        for (int ip = 0; ip < NP; ++ip) {
            // I for rows (2ip, 2ip+1) via packed FMA (2 instr per element pair chain)
            v2f t = __builtin_elementwise_fma(xp3[ip], (v2f){w1.w, w1.w}, (v2f){bb, bb});
            t     = __builtin_elementwise_fma(xp2[ip], (v2f){w1.z, w1.z}, t);
            t     = __builtin_elementwise_fma(xp1[ip], (v2f){w1.y, w1.y}, t);
            const v2f I2 = __builtin_elementwise_fma(xp0[ip], (v2f){w1.x, w1.x}, t);

#pragma unroll
            for (int u = 0; u < 2; ++u) {
                const float I = u ? I2.y : I2.x;
                const int   i = 2 * ip + u;

                const float r = __builtin_amdgcn_rcpf(I);
                const float c = __builtin_ceilf(r);
                int idx = (int)__builtin_amdgcn_fmed3f(c, 0.0f, 17.0f) << 2;

                // per-element guard: near a breakpoint -> exact 16-step fallback
                if (__builtin_expect(
                        (unsigned long long)__ballot(fabsf((r - c) + 0.5f) > GTHR), 0)) {
                    float v = 0.0f;
                    int cnt = 0;
#pragma unroll
                    for (int s = 0; s < TSTEPS; ++s) {
                        v += I;
                        cnt += (v < 1.0f) ? 1 : 0;
                    }
                    idx = (cnt + 1) << 2;          // exact for all lanes
                }

                const float A = __int_as_float(
                    __builtin_amdgcn_ds_bpermute(idx, table_reg));
                // one packed FMA updates (out0, out1) together; A splat -> op_sel
                acc[i] = __builtin_elementwise_fma((v2f){A, A}, w2ab, acc[i]);
            }
        }
    }

    // ---- epilogue: value-halving wave reduction (verified R10/R12) ----
    // logical index j = 2*row_local + o
    float v[16];
#pragma unroll
    for (int i = 0; i < NB; ++i) {
        v[2 * i + 0] = acc[i].x;
        v[2 * i + 1] = acc[i].y;
    }

    {   // off=32: 16 -> 8 values
        const bool up = (lane & 32) != 0;
#pragma unroll
        for (int k = 0; k < 8; ++k) {
            const float mine = up ? v[k] : v[k + 8];
            const float recv = __shfl_xor(mine, 32, 64);
            v[k] = (up ? v[k + 8] : v[k]) + recv;
        }
    }
    {   // off=16: 8 -> 4
        const bool up = (lane & 16) != 0;
#pragma unroll
        for (int k = 0; k < 4; ++k) {
            const float mine = up ? v[k] : v[k + 4];
            const float recv = __shfl_xor(mine, 16, 64);
            v[k] = (up ? v[k + 4] : v[k]) + recv;
        }
    }
    {   // off=8: 4 -> 2
        const bool up = (lane & 8) != 0;
#pragma unroll
        for (int k = 0; k < 2; ++k) {
            const float mine = up ? v[k] : v[k + 2];
            const float recv = __shfl_xor(mine, 8, 64);
            v[k] = (up ? v[k + 2] : v[k]) + recv;
        }
    }
    {   // off=4: 2 -> 1; value index = (lane>>2)&15
        const bool up = (lane & 4) != 0;
        const float mine = up ? v[0] : v[1];
        const float recv = __shfl_xor(mine, 4, 64);
        v[0] = (up ? v[1] : v[0]) + recv;
    }
    float tot = v[0];
    tot += __shfl_xor(tot, 1, 64);
    tot += __shfl_xor(tot, 2, 64);

    __shared__ float red[4][16];
    if ((lane & 3) == 0) red[tid >> 6][lane >> 2] = tot;
    __syncthreads();

    if (tid < 16) {
        const float s = (red[0][tid] + red[1][tid]) + (red[2][tid] + red[3][tid]);
        const int i = tid >> 1;
        const int o = tid & 1;
        if (b0 + i < B)
            out[(b0 + i) * 2 + o] = s + b2[o] * (1.0f - 0x1p-16f);
    }
}

extern "C" void kernel_launch(void* const* d_in, const int* in_sizes, int n_in,
                              void* d_out, int out_size, void* d_ws, size_t ws_size,
                              hipStream_t stream) {
    const float* x  = (const float*)d_in[0];
    const float* W1 = (const float*)d_in[1];
    const float* b1 = (const float*)d_in[2];
    const float* W2 = (const float*)d_in[3];
    const float* b2 = (const float*)d_in[4];
    float* out = (float*)d_out;

    const int B = in_sizes[0] / 4;   // 16384
    const int H = in_sizes[2];       // 4096

    const int grid = (B + NB - 1) / NB;
    dqsn_fwd<<<grid, 256, 0, stream>>>(x, W1, b1, W2, b2, out, B, H);
}

// Round 15
// 32.023 us; speedup vs baseline: 1.0498x; 1.0498x over previous
//
#include <hip/hip_runtime.h>

// DQSN forward (v9/R12 — the verified optimum, restored verbatim).
//
// out[b,o] = sum_h W2[o,h] * A[b,h] + b2[o] * (1 - 2^-16)
// A depends only on n = first j in 1..16 with fp32-cumsum_j(I) >= 1
// (hard reset to exactly 0.0 -> exactly periodic spike train, period n).
// n = med3(ceil(rcp(I)), 0, 17); provably equals the fp32-cumsum crossing
// outside the |r - nearest-int| < GUARD band (rcp err ~2e-6, cumsum shift
// <= 1.6e-5); in-band elements (P ~ 1e-4) fall back to the exact 16-step
// simulation, keeping decisions bit-faithful to the reference dynamics.
// A(n) via per-lane register table + ds_bpermute.

constexpr int TSTEPS = 16;
constexpr int NB = 8;                  // batch rows per block (grid = 2048)
constexpr float GUARD = 4e-5f;
constexpr float GTHR  = 0.5f - GUARD;

__global__ __launch_bounds__(256) void dqsn_fwd(
    const float* __restrict__ x,
    const float* __restrict__ W1,
    const float* __restrict__ b1,
    const float* __restrict__ W2,
    const float* __restrict__ b2,
    float* __restrict__ out,
    int B, int H)
{
    const int tid  = threadIdx.x;
    const int lane = tid & 63;
    const int b0   = blockIdx.x * NB;

    // per-lane A(n) table: lane l (1..16) holds A for period n=l.
    // lanes 0 and 17+ hold 0.0 (n=0: I<=0; n=17: no spike within 16 steps).
    float tval = 0.0f;
    if (lane >= 1 && lane <= TSTEPS) {
        unsigned mm = 0;
        for (int k = lane; k <= TSTEPS; k += lane) mm |= 1u << (k - 1);
        tval = (float)mm * 0x1p-16f;   // exact: mm < 2^17
    }
    const int table_reg = __float_as_int(tval);

    // x rows for this block: block-uniform -> scalar regs
    float xs0[NB], xs1[NB], xs2[NB], xs3[NB];
#pragma unroll
    for (int i = 0; i < NB; ++i) {
        const int bi = (b0 + i < B) ? (b0 + i) : (B - 1);
        xs0[i] = x[bi * 4 + 0];
        xs1[i] = x[bi * 4 + 1];
        xs2[i] = x[bi * 4 + 2];
        xs3[i] = x[bi * 4 + 3];
    }

    float acc0[NB], acc1[NB];
#pragma unroll
    for (int i = 0; i < NB; ++i) { acc0[i] = 0.0f; acc1[i] = 0.0f; }

    // tight runtime loop, minimal live-set (one element in flight)
    for (int h = tid; h < H; h += 256) {
        const float4 w1 = *reinterpret_cast<const float4*>(W1 + (size_t)h * 4);
        const float bb  = b1[h];
        const float w2a = W2[h];
        const float w2b = W2[H + h];

#pragma unroll
        for (int i = 0; i < NB; ++i) {
            const float I = fmaf(xs0[i], w1.x,
                            fmaf(xs1[i], w1.y,
                            fmaf(xs2[i], w1.z,
                            fmaf(xs3[i], w1.w, bb))));

            const float r = __builtin_amdgcn_rcpf(I);
            const float c = __builtin_ceilf(r);
            int idx = (int)__builtin_amdgcn_fmed3f(c, 0.0f, 17.0f) << 2;

            // per-element guard: near a breakpoint -> exact 16-step fallback
            if (__builtin_expect(
                    (unsigned long long)__ballot(fabsf((r - c) + 0.5f) > GTHR), 0)) {
                float v = 0.0f;
                int cnt = 0;
#pragma unroll
                for (int t = 0; t < TSTEPS; ++t) {
                    v += I;
                    cnt += (v < 1.0f) ? 1 : 0;
                }
                idx = (cnt + 1) << 2;          // exact for all lanes
            }

            const float A = __int_as_float(__builtin_amdgcn_ds_bpermute(idx, table_reg));
            acc0[i] = fmaf(A, w2a, acc0[i]);
            acc1[i] = fmaf(A, w2b, acc1[i]);
        }
    }

    // ---- epilogue: value-halving wave reduction ----
    // logical index j = 2*row_local + o
    float v[16];
#pragma unroll
    for (int i = 0; i < NB; ++i) {
        v[2 * i + 0] = acc0[i];
        v[2 * i + 1] = acc1[i];
    }

    {   // off=32: 16 -> 8 values
        const bool up = (lane & 32) != 0;
#pragma unroll
        for (int k = 0; k < 8; ++k) {
            const float mine = up ? v[k] : v[k + 8];
            const float recv = __shfl_xor(mine, 32, 64);
            v[k] = (up ? v[k + 8] : v[k]) + recv;
        }
    }
    {   // off=16: 8 -> 4
        const bool up = (lane & 16) != 0;
#pragma unroll
        for (int k = 0; k < 4; ++k) {
            const float mine = up ? v[k] : v[k + 4];
            const float recv = __shfl_xor(mine, 16, 64);
            v[k] = (up ? v[k + 4] : v[k]) + recv;
        }
    }
    {   // off=8: 4 -> 2
        const bool up = (lane & 8) != 0;
#pragma unroll
        for (int k = 0; k < 2; ++k) {
            const float mine = up ? v[k] : v[k + 2];
            const float recv = __shfl_xor(mine, 8, 64);
            v[k] = (up ? v[k + 2] : v[k]) + recv;
        }
    }
    {   // off=4: 2 -> 1; value index = (lane>>2)&15
        const bool up = (lane & 4) != 0;
        const float mine = up ? v[0] : v[1];
        const float recv = __shfl_xor(mine, 4, 64);
        v[0] = (up ? v[1] : v[0]) + recv;
    }
    float tot = v[0];
    tot += __shfl_xor(tot, 1, 64);
    tot += __shfl_xor(tot, 2, 64);

    __shared__ float red[4][16];
    if ((lane & 3) == 0) red[tid >> 6][lane >> 2] = tot;
    __syncthreads();

    if (tid < 16) {
        const float s = (red[0][tid] + red[1][tid]) + (red[2][tid] + red[3][tid]);
        const int i = tid >> 1;
        const int o = tid & 1;
        if (b0 + i < B)
            out[(b0 + i) * 2 + o] = s + b2[o] * (1.0f - 0x1p-16f);
    }
}

extern "C" void kernel_launch(void* const* d_in, const int* in_sizes, int n_in,
                              void* d_out, int out_size, void* d_ws, size_t ws_size,
                              hipStream_t stream) {
    const float* x  = (const float*)d_in[0];
    const float* W1 = (const float*)d_in[1];
    const float* b1 = (const float*)d_in[2];
    const float* W2 = (const float*)d_in[3];
    const float* b2 = (const float*)d_in[4];
    float* out = (float*)d_out;

    const int B = in_sizes[0] / 4;   // 16384
    const int H = in_sizes[2];       // 4096

    const int grid = (B + NB - 1) / NB;
    dqsn_fwd<<<grid, 256, 0, stream>>>(x, W1, b1, W2, b2, out, B, H);
}